// Round 14
// baseline (305.894 us; speedup 1.0000x reference)
//
#include <hip/hip_runtime.h>
#include <math.h>

#define N 8192
#define C 10
#define NUM_ITERS 5
#define FBLOCK 1024        /* 16 waves, 1 block/CU, 4 waves/SIMD */
#define IBLK 32            /* i's per block */
#define NBLK (N / IBLK)    /* 256 blocks = 1 per CU */
#define JW (N / 16)        /* 512 j's per wave */
#define NS (JW / 32)       /* 16 s-iters per wave, 32 j's each */
#define LOG2E 1.44269504088896340736f
#define C3 (LOG2E / 64.0f)

typedef _Float16 half8 __attribute__((ext_vector_type(8)));
typedef _Float16 half4 __attribute__((ext_vector_type(4)));
typedef _Float16 half2 __attribute__((ext_vector_type(2)));
typedef float f32x4 __attribute__((ext_vector_type(4)));
typedef float f32x16 __attribute__((ext_vector_type(16)));

// ws layout:
//   ajs half8[N]          128KB ; ajb half8[N] 128KB
//   pf0/pf1 f16[N/16][16][16]   : probs, J-TILED
//   scrap (>=2MB offset)        : probe sinks
#define WS_AJS 0
#define WS_AJB (N * 16)
#define WS_PF0 (N * 32)
#define WS_PF1 (N * 64)
#define WS_SCRAP (2 * 1024 * 1024)
#define PFIDX(n, c) ((((n) >> 4) * 16 + (c)) * 16 + ((n) & 15))

static __device__ __forceinline__ unsigned int pkexp(float a, float b) {
    float ea = __builtin_amdgcn_exp2f(a);
    float eb = __builtin_amdgcn_exp2f(b);
    return __builtin_bit_cast(unsigned int, __builtin_amdgcn_cvt_pkrtz(ea, eb));
}

static __device__ __forceinline__ half8 rdfrag(const unsigned int* R, int q) {
    uint2 lo = *(const uint2*)&R[2 * q];
    uint2 hi = *(const uint2*)&R[8 + 2 * q];
    half2 a = __builtin_bit_cast(half2, lo.x);
    half2 b = __builtin_bit_cast(half2, lo.y);
    half2 c = __builtin_bit_cast(half2, hi.x);
    half2 d = __builtin_bit_cast(half2, hi.y);
    half8 r = {a[0], a[1], b[0], b[1], c[0], c[1], d[0], d[1]};
    return r;
}

// once per launch: aug features + softmax(unaries) -> pf0 (tiled); zero rows 10..15 both
__global__ __launch_bounds__(256) void init_kernel(
    const float* __restrict__ unaries, const float* __restrict__ feat,
    half8* __restrict__ ajs8, half8* __restrict__ ajb8,
    _Float16* __restrict__ pf0, _Float16* __restrict__ pf1) {
    int n = blockIdx.x * 256 + threadIdx.x;
    float f6[6];
#pragma unroll
    for (int d = 0; d < 6; ++d) f6[d] = feat[d * N + n];
    float h3 = 0.5f * (f6[0] * f6[0] + f6[1] * f6[1] + f6[2] * f6[2]);
    float h6v = h3 + 0.5f * (f6[3] * f6[3] + f6[4] * f6[4] + f6[5] * f6[5]);
    half8 a = {};
    a[0] = (_Float16)(f6[0] * C3);
    a[1] = (_Float16)(f6[1] * C3);
    a[2] = (_Float16)(f6[2] * C3);
    a[6] = (_Float16)(-h3 * C3);
    a[7] = (_Float16)1.0f;
    ajs8[n] = a;
    half8 b;
#pragma unroll
    for (int d = 0; d < 6; ++d) b[d] = (_Float16)(f6[d] * LOG2E);
    b[6] = (_Float16)(-h6v * LOG2E);
    b[7] = (_Float16)1.0f;
    ajb8[n] = b;

    float q[C];
#pragma unroll
    for (int c = 0; c < C; ++c) q[c] = unaries[c * N + n];
    float m = q[0];
#pragma unroll
    for (int c = 1; c < C; ++c) m = fmaxf(m, q[c]);
    float e[C], s = 0.0f;
#pragma unroll
    for (int c = 0; c < C; ++c) {
        e[c] = __builtin_amdgcn_exp2f((q[c] - m) * LOG2E);
        s += e[c];
    }
    float inv = 1.0f / s;
#pragma unroll
    for (int c = 0; c < C; ++c) pf0[PFIDX(n, c)] = (_Float16)(e[c] * inv);
#pragma unroll
    for (int c = C; c < 16; ++c) {
        pf0[PFIDX(n, c)] = (_Float16)0.0f;
        pf1[PFIDX(n, c)] = (_Float16)0.0f;
    }
}

// ============================ champion (R13, 162us) ============================
__global__ __launch_bounds__(FBLOCK, 4) void fused_kernel(
    const float* __restrict__ unaries, const float* __restrict__ feat,
    const float* __restrict__ SW, const float* __restrict__ BW,
    const float* __restrict__ CM,
    const char* __restrict__ ajs_c, const char* __restrict__ ajb_c,
    const _Float16* __restrict__ pf_in, _Float16* __restrict__ pf_out,
    float* __restrict__ out, int is_last) {
    __shared__ union {
        unsigned int wt[16][2][32][18];
        float rbuf[16 * 1024];
    } sm;
    int t = threadIdx.x;
    int i0 = blockIdx.x * IBLK;
    int lane = t & 63;
    int w = t >> 6;
    int il = lane & 15;
    int quad = lane >> 4;
    int li = lane & 31;
    int hs = lane >> 5;
    const f32x4 zero4 = {0.f, 0.f, 0.f, 0.f};
    const f32x16 zero16 = {};

    half8 b1s, b1b;
    {
        int i = i0 + li;
        float g0 = feat[0 * N + i], g1 = feat[1 * N + i], g2 = feat[2 * N + i];
        float g3 = feat[3 * N + i], g4 = feat[4 * N + i], g5 = feat[5 * N + i];
        float h3 = 0.5f * (g0 * g0 + g1 * g1 + g2 * g2);
        float h6v = h3 + 0.5f * (g3 * g3 + g4 * g4 + g5 * g5);
        half4 slo = {(_Float16)g0, (_Float16)g1, (_Float16)g2, (_Float16)0.0f};
        half4 shi = {(_Float16)0.0f, (_Float16)0.0f, (_Float16)1.0f, (_Float16)(-h3 * C3)};
        half4 blo = {(_Float16)g0, (_Float16)g1, (_Float16)g2, (_Float16)g3};
        half4 bhi = {(_Float16)g4, (_Float16)g5, (_Float16)1.0f, (_Float16)(-h6v * LOG2E)};
        half4 sv = hs ? shi : slo;
        half4 bv = hs ? bhi : blo;
        half8 t1 = {sv[0], sv[1], sv[2], sv[3], (_Float16)0.0f, (_Float16)0.0f,
                    (_Float16)0.0f, (_Float16)0.0f};
        half8 t2 = {bv[0], bv[1], bv[2], bv[3], (_Float16)0.0f, (_Float16)0.0f,
                    (_Float16)0.0f, (_Float16)0.0f};
        b1s = t1;
        b1b = t2;
    }

    f32x4 as0 = zero4, as1 = zero4, ab0 = zero4, ab1 = zero4;
    int jw = w * JW;
    const half4* pfv = (const half4*)pf_in;
    unsigned int* Ws = &sm.wt[w][0][li][0];
    unsigned int* Wb = &sm.wt[w][1][li][0];
    const unsigned int* R0s = &sm.wt[w][0][il][0];
    const unsigned int* R1s = &sm.wt[w][0][16 + il][0];
    const unsigned int* R0b = &sm.wt[w][1][il][0];
    const unsigned int* R1b = &sm.wt[w][1][16 + il][0];

    {
        int ph = w & 3;
        if (ph == 1) __builtin_amdgcn_s_sleep(2);
        else if (ph == 2) __builtin_amdgcn_s_sleep(4);
        else if (ph == 3) __builtin_amdgcn_s_sleep(6);
    }

    for (int k = 0; k < NS; ++k) {
        int j0 = jw + k * 32;
        half4 av_s = *(const half4*)(ajs_c + (size_t)(j0 + li) * 16 + hs * 8);
        half4 av_b = *(const half4*)(ajb_c + (size_t)(j0 + li) * 16 + hs * 8);
        half4 cp0 = pfv[((j0 >> 4) * 16 + il) * 4 + quad];
        half4 cp1 = pfv[(((j0 >> 4) + 1) * 16 + il) * 4 + quad];
        half8 A_s = {av_s[0], av_s[1], av_s[2], av_s[3], (_Float16)0.0f,
                     (_Float16)0.0f, (_Float16)0.0f, (_Float16)0.0f};
        half8 A_b = {av_b[0], av_b[1], av_b[2], av_b[3], (_Float16)0.0f,
                     (_Float16)0.0f, (_Float16)0.0f, (_Float16)0.0f};
        half8 Bp = {cp0[0], cp0[1], cp0[2], cp0[3], cp1[0], cp1[1], cp1[2], cp1[3]};

        __builtin_amdgcn_s_setprio(1);
        f32x16 d1s = __builtin_amdgcn_mfma_f32_32x32x16_f16(A_s, b1s, zero16, 0, 0, 0);
        f32x16 d1b = __builtin_amdgcn_mfma_f32_32x32x16_f16(A_b, b1b, zero16, 0, 0, 0);
        __builtin_amdgcn_s_setprio(0);

        {
            uint2 v;
            v.x = pkexp(d1s[0], d1s[1]);  v.y = pkexp(d1s[2], d1s[3]);
            *(uint2*)&Ws[0 + 2 * hs] = v;
            v.x = pkexp(d1s[4], d1s[5]);  v.y = pkexp(d1s[6], d1s[7]);
            *(uint2*)&Ws[4 + 2 * hs] = v;
            v.x = pkexp(d1s[8], d1s[9]);  v.y = pkexp(d1s[10], d1s[11]);
            *(uint2*)&Ws[8 + 2 * hs] = v;
            v.x = pkexp(d1s[12], d1s[13]); v.y = pkexp(d1s[14], d1s[15]);
            *(uint2*)&Ws[12 + 2 * hs] = v;
            v.x = pkexp(d1b[0], d1b[1]);  v.y = pkexp(d1b[2], d1b[3]);
            *(uint2*)&Wb[0 + 2 * hs] = v;
            v.x = pkexp(d1b[4], d1b[5]);  v.y = pkexp(d1b[6], d1b[7]);
            *(uint2*)&Wb[4 + 2 * hs] = v;
            v.x = pkexp(d1b[8], d1b[9]);  v.y = pkexp(d1b[10], d1b[11]);
            *(uint2*)&Wb[8 + 2 * hs] = v;
            v.x = pkexp(d1b[12], d1b[13]); v.y = pkexp(d1b[14], d1b[15]);
            *(uint2*)&Wb[12 + 2 * hs] = v;
        }
        half8 A00 = rdfrag(R0s, quad);
        half8 A01 = rdfrag(R1s, quad);
        half8 A10 = rdfrag(R0b, quad);
        half8 A11 = rdfrag(R1b, quad);
        __builtin_amdgcn_s_setprio(1);
        as0 = __builtin_amdgcn_mfma_f32_16x16x32_f16(A00, Bp, as0, 0, 0, 0);
        as1 = __builtin_amdgcn_mfma_f32_16x16x32_f16(A01, Bp, as1, 0, 0, 0);
        ab0 = __builtin_amdgcn_mfma_f32_16x16x32_f16(A10, Bp, ab0, 0, 0, 0);
        ab1 = __builtin_amdgcn_mfma_f32_16x16x32_f16(A11, Bp, ab1, 0, 0, 0);
        __builtin_amdgcn_s_setprio(0);
    }

    __syncthreads();
    {
        float* rb = sm.rbuf + w * 1024;
#pragma unroll
        for (int r = 0; r < 4; ++r) {
            rb[r * 64 + lane]       = as0[r];
            rb[256 + r * 64 + lane] = as1[r];
            rb[512 + r * 64 + lane] = ab0[r];
            rb[768 + r * 64 + lane] = ab1[r];
        }
    }
    __syncthreads();
    {
        float tot = 0.f;
#pragma unroll
        for (int w2 = 0; w2 < 16; ++w2) tot += sm.rbuf[w2 * 1024 + t];
        sm.rbuf[t] = tot;
    }
    __syncthreads();

    if (t < IBLK) {
        int i = i0 + t;
        int sub = t >> 4, ql = (t & 15) >> 2, rr = t & 3;
        float sp[C], bl[C];
#pragma unroll
        for (int c = 0; c < C; ++c) {
            int base = sub * 256 + rr * 64 + ql * 16 + c;
            sp[c] = sm.rbuf[base];
            bl[c] = sm.rbuf[base + 512];
        }
        float msg[C];
#pragma unroll
        for (int c = 0; c < C; ++c) {
            float m = 0.f;
#pragma unroll
            for (int kk = 0; kk < C; ++kk)
                m += SW[c * C + kk] * sp[kk] + BW[c * C + kk] * bl[kk];
            msg[c] = m;
        }
        float qq[C];
#pragma unroll
        for (int c = 0; c < C; ++c) {
            float pw = 0.f;
#pragma unroll
            for (int kk = 0; kk < C; ++kk) pw += CM[c * C + kk] * msg[kk];
            qq[c] = unaries[c * N + i] - pw;
        }
        if (is_last) {
#pragma unroll
            for (int c = 0; c < C; ++c) out[c * N + i] = qq[c];
        } else {
            float m = qq[0];
#pragma unroll
            for (int c = 1; c < C; ++c) m = fmaxf(m, qq[c]);
            float e[C], s = 0.0f;
#pragma unroll
            for (int c = 0; c < C; ++c) {
                e[c] = __builtin_amdgcn_exp2f((qq[c] - m) * LOG2E);
                s += e[c];
            }
            float inv = 1.0f / s;
#pragma unroll
            for (int c = 0; c < C; ++c) pf_out[PFIDX(i, c)] = (_Float16)(e[c] * inv);
        }
    }
}

// =================== probes (diagnostic; removed next round) ===================

// PROBE A: exact replica of the champion main loop, duty 3 (~75us -> owns top-5
// counter slots). Reads real buffers; writes acc to scrap.
__global__ __launch_bounds__(FBLOCK, 4) void probe_full(
    const char* __restrict__ ajs_c, const char* __restrict__ ajb_c,
    const _Float16* __restrict__ pf_in, float* __restrict__ dst) {
    __shared__ unsigned int wt[16][2][32][18];
    int t = threadIdx.x;
    int lane = t & 63;
    int w = t >> 6;
    int il = lane & 15;
    int quad = lane >> 4;
    int li = lane & 31;
    int hs = lane >> 5;
    const f32x16 zero16 = {};
    const f32x4 zero4 = {0.f, 0.f, 0.f, 0.f};

    half8 b1s, b1b;
    {
        half4 sv = *(const half4*)(ajs_c + (size_t)li * 16 + hs * 8);
        half4 bv = *(const half4*)(ajb_c + (size_t)li * 16 + hs * 8);
        half8 t1 = {sv[0], sv[1], sv[2], sv[3], (_Float16)0.0f, (_Float16)0.0f,
                    (_Float16)0.0f, (_Float16)0.0f};
        half8 t2 = {bv[0], bv[1], bv[2], bv[3], (_Float16)0.0f, (_Float16)0.0f,
                    (_Float16)0.0f, (_Float16)0.0f};
        b1s = t1;
        b1b = t2;
    }
    f32x4 as0 = zero4, as1 = zero4, ab0 = zero4, ab1 = zero4;
    int jw = w * JW;
    unsigned int* Ws = &wt[w][0][li][0];
    unsigned int* Wb = &wt[w][1][li][0];
    const unsigned int* R0s = &wt[w][0][il][0];
    const unsigned int* R1s = &wt[w][0][16 + il][0];
    const unsigned int* R0b = &wt[w][1][il][0];
    const unsigned int* R1b = &wt[w][1][16 + il][0];
    {
        int ph = w & 3;
        if (ph == 1) __builtin_amdgcn_s_sleep(2);
        else if (ph == 2) __builtin_amdgcn_s_sleep(4);
        else if (ph == 3) __builtin_amdgcn_s_sleep(6);
    }

    for (int d = 0; d < 3; ++d) {
        const char* as_ = ajs_c + (d & 1) * 16;
        const char* ab_ = ajb_c + (d & 1) * 16;
        const half4* pfv = (const half4*)pf_in + (d & 1);
        for (int k = 0; k < NS; ++k) {
            int j0 = jw + k * 32;
            half4 av_s = *(const half4*)(as_ + (size_t)(j0 + li) * 16 + hs * 8);
            half4 av_b = *(const half4*)(ab_ + (size_t)(j0 + li) * 16 + hs * 8);
            half4 cp0 = pfv[((j0 >> 4) * 16 + il) * 4 + quad];
            half4 cp1 = pfv[(((j0 >> 4) + 1) * 16 + il) * 4 + quad];
            half8 A_s = {av_s[0], av_s[1], av_s[2], av_s[3], (_Float16)0.0f,
                         (_Float16)0.0f, (_Float16)0.0f, (_Float16)0.0f};
            half8 A_b = {av_b[0], av_b[1], av_b[2], av_b[3], (_Float16)0.0f,
                         (_Float16)0.0f, (_Float16)0.0f, (_Float16)0.0f};
            half8 Bp = {cp0[0], cp0[1], cp0[2], cp0[3], cp1[0], cp1[1], cp1[2], cp1[3]};

            __builtin_amdgcn_s_setprio(1);
            f32x16 d1s = __builtin_amdgcn_mfma_f32_32x32x16_f16(A_s, b1s, zero16, 0, 0, 0);
            f32x16 d1b = __builtin_amdgcn_mfma_f32_32x32x16_f16(A_b, b1b, zero16, 0, 0, 0);
            __builtin_amdgcn_s_setprio(0);
            {
                uint2 v;
                v.x = pkexp(d1s[0], d1s[1]);  v.y = pkexp(d1s[2], d1s[3]);
                *(uint2*)&Ws[0 + 2 * hs] = v;
                v.x = pkexp(d1s[4], d1s[5]);  v.y = pkexp(d1s[6], d1s[7]);
                *(uint2*)&Ws[4 + 2 * hs] = v;
                v.x = pkexp(d1s[8], d1s[9]);  v.y = pkexp(d1s[10], d1s[11]);
                *(uint2*)&Ws[8 + 2 * hs] = v;
                v.x = pkexp(d1s[12], d1s[13]); v.y = pkexp(d1s[14], d1s[15]);
                *(uint2*)&Ws[12 + 2 * hs] = v;
                v.x = pkexp(d1b[0], d1b[1]);  v.y = pkexp(d1b[2], d1b[3]);
                *(uint2*)&Wb[0 + 2 * hs] = v;
                v.x = pkexp(d1b[4], d1b[5]);  v.y = pkexp(d1b[6], d1b[7]);
                *(uint2*)&Wb[4 + 2 * hs] = v;
                v.x = pkexp(d1b[8], d1b[9]);  v.y = pkexp(d1b[10], d1b[11]);
                *(uint2*)&Wb[8 + 2 * hs] = v;
                v.x = pkexp(d1b[12], d1b[13]); v.y = pkexp(d1b[14], d1b[15]);
                *(uint2*)&Wb[12 + 2 * hs] = v;
            }
            half8 A00 = rdfrag(R0s, quad);
            half8 A01 = rdfrag(R1s, quad);
            half8 A10 = rdfrag(R0b, quad);
            half8 A11 = rdfrag(R1b, quad);
            __builtin_amdgcn_s_setprio(1);
            as0 = __builtin_amdgcn_mfma_f32_16x16x32_f16(A00, Bp, as0, 0, 0, 0);
            as1 = __builtin_amdgcn_mfma_f32_16x16x32_f16(A01, Bp, as1, 0, 0, 0);
            ab0 = __builtin_amdgcn_mfma_f32_16x16x32_f16(A10, Bp, ab0, 0, 0, 0);
            ab1 = __builtin_amdgcn_mfma_f32_16x16x32_f16(A11, Bp, ab1, 0, 0, 0);
            __builtin_amdgcn_s_setprio(0);
        }
    }
    float* dv = dst + ((size_t)blockIdx.x * FBLOCK + t) * 4;
    dv[0] = as0[0] + as1[1];
    dv[1] = ab0[2] + ab1[3];
    dv[2] = as0[2] + ab1[0];
    dv[3] = as1[3] + ab0[1];
}

// PROBE B: loads + G1 + G2 only (no exp/cvt/LDS; A-frags = bitcast of d1),
// duty 12. Time inferred by subtraction from dur_us. MFMA+load floor.
__global__ __launch_bounds__(FBLOCK, 4) void probe_floor(
    const char* __restrict__ ajs_c, const char* __restrict__ ajb_c,
    const _Float16* __restrict__ pf_in, float* __restrict__ dst) {
    int t = threadIdx.x;
    int lane = t & 63;
    int w = t >> 6;
    int il = lane & 15;
    int quad = lane >> 4;
    int li = lane & 31;
    int hs = lane >> 5;
    const f32x16 zero16 = {};
    const f32x4 zero4 = {0.f, 0.f, 0.f, 0.f};

    half8 b1s, b1b;
    {
        half4 sv = *(const half4*)(ajs_c + (size_t)li * 16 + hs * 8);
        half4 bv = *(const half4*)(ajb_c + (size_t)li * 16 + hs * 8);
        half8 t1 = {sv[0], sv[1], sv[2], sv[3], (_Float16)0.0f, (_Float16)0.0f,
                    (_Float16)0.0f, (_Float16)0.0f};
        half8 t2 = {bv[0], bv[1], bv[2], bv[3], (_Float16)0.0f, (_Float16)0.0f,
                    (_Float16)0.0f, (_Float16)0.0f};
        b1s = t1;
        b1b = t2;
    }
    f32x4 as0 = zero4, as1 = zero4, ab0 = zero4, ab1 = zero4;
    int jw = w * JW;

    for (int d = 0; d < 12; ++d) {
        const char* as_ = ajs_c + (d & 1) * 16;
        const char* ab_ = ajb_c + (d & 1) * 16;
        const half4* pfv = (const half4*)pf_in + (d & 1);
        for (int k = 0; k < NS; ++k) {
            int j0 = jw + k * 32;
            half4 av_s = *(const half4*)(as_ + (size_t)(j0 + li) * 16 + hs * 8);
            half4 av_b = *(const half4*)(ab_ + (size_t)(j0 + li) * 16 + hs * 8);
            half4 cp0 = pfv[((j0 >> 4) * 16 + il) * 4 + quad];
            half4 cp1 = pfv[(((j0 >> 4) + 1) * 16 + il) * 4 + quad];
            half8 A_s = {av_s[0], av_s[1], av_s[2], av_s[3], (_Float16)0.0f,
                         (_Float16)0.0f, (_Float16)0.0f, (_Float16)0.0f};
            half8 A_b = {av_b[0], av_b[1], av_b[2], av_b[3], (_Float16)0.0f,
                         (_Float16)0.0f, (_Float16)0.0f, (_Float16)0.0f};
            half8 Bp = {cp0[0], cp0[1], cp0[2], cp0[3], cp1[0], cp1[1], cp1[2], cp1[3]};

            f32x16 d1s = __builtin_amdgcn_mfma_f32_32x32x16_f16(A_s, b1s, zero16, 0, 0, 0);
            f32x16 d1b = __builtin_amdgcn_mfma_f32_32x32x16_f16(A_b, b1b, zero16, 0, 0, 0);
            // bitcast halves of d1 as garbage A-frags (keeps G1 live, no exp/LDS)
            f32x4 t0 = {d1s[0], d1s[1], d1s[2], d1s[3]};
            f32x4 t1 = {d1s[4], d1s[5], d1s[6], d1s[7]};
            f32x4 t2 = {d1b[0], d1b[1], d1b[2], d1b[3]};
            f32x4 t3 = {d1b[4], d1b[5], d1b[6], d1b[7]};
            half8 A00 = __builtin_bit_cast(half8, t0);
            half8 A01 = __builtin_bit_cast(half8, t1);
            half8 A10 = __builtin_bit_cast(half8, t2);
            half8 A11 = __builtin_bit_cast(half8, t3);
            as0 = __builtin_amdgcn_mfma_f32_16x16x32_f16(A00, Bp, as0, 0, 0, 0);
            as1 = __builtin_amdgcn_mfma_f32_16x16x32_f16(A01, Bp, as1, 0, 0, 0);
            ab0 = __builtin_amdgcn_mfma_f32_16x16x32_f16(A10, Bp, ab0, 0, 0, 0);
            ab1 = __builtin_amdgcn_mfma_f32_16x16x32_f16(A11, Bp, ab1, 0, 0, 0);
        }
    }
    float* dv = dst + ((size_t)blockIdx.x * FBLOCK + t) * 4;
    dv[0] = as0[0] + as1[1];
    dv[1] = ab0[2] + ab1[3];
    dv[2] = as0[2] + ab1[0];
    dv[3] = as1[3] + ab0[1];
}

extern "C" void kernel_launch(void* const* d_in, const int* in_sizes, int n_in,
                              void* d_out, int out_size, void* d_ws, size_t ws_size,
                              hipStream_t stream) {
    const float* unaries = (const float*)d_in[0];   // [10, 8192]
    const float* feat    = (const float*)d_in[1];   // [6, 8192]
    const float* SW      = (const float*)d_in[2];   // [10,10]
    const float* BW      = (const float*)d_in[3];   // [10,10]
    const float* CM      = (const float*)d_in[4];   // [10,10]
    float* out = (float*)d_out;

    char* ws = (char*)d_ws;
    half8* ajs    = (half8*)(ws + WS_AJS);
    half8* ajb    = (half8*)(ws + WS_AJB);
    _Float16* pf0 = (_Float16*)(ws + WS_PF0);
    _Float16* pf1 = (_Float16*)(ws + WS_PF1);
    float* scrap  = (float*)(ws + WS_SCRAP);

    init_kernel<<<N / 256, 256, 0, stream>>>(unaries, feat, ajs, ajb, pf0, pf1);
    const _Float16* pin = pf0;
    _Float16* pout = pf1;
    for (int it = 1; it <= NUM_ITERS; ++it) {
        fused_kernel<<<NBLK, FBLOCK, 0, stream>>>(
            unaries, feat, SW, BW, CM, (const char*)ajs, (const char*)ajb,
            pin, pout, out, it == NUM_ITERS ? 1 : 0);
        const _Float16* tmp = pout;
        pout = (_Float16*)pin;
        pin = tmp;
    }
    // -------- diagnostics (scrap-only; removed next round) --------
    probe_full<<<NBLK, FBLOCK, 0, stream>>>((const char*)ajs, (const char*)ajb,
                                            pf0, scrap);
    probe_floor<<<NBLK, FBLOCK, 0, stream>>>((const char*)ajs, (const char*)ajb,
                                             pf0, scrap + 4 * 1024 * 1024);
}

// Round 15
// 244.245 us; speedup vs baseline: 1.2524x; 1.2524x over previous
//
#include <hip/hip_runtime.h>
#include <math.h>

#define N 8192
#define C 10
#define NUM_ITERS 5
#define FBLOCK 1024        /* 16 waves, 1 block/CU, 4 waves/SIMD */
#define IBLK 32            /* i's per block */
#define NBLK (N / IBLK)    /* 256 blocks = 1 per CU */
#define JW (N / 16)        /* 512 j's per wave */
#define NS (JW / 32)       /* 16 s-iters per wave, 32 j's each */
#define LOG2E 1.44269504088896340736f
#define C3 (LOG2E / 64.0f)

typedef _Float16 half8 __attribute__((ext_vector_type(8)));
typedef _Float16 half4 __attribute__((ext_vector_type(4)));
typedef _Float16 half2 __attribute__((ext_vector_type(2)));
typedef float f32x4 __attribute__((ext_vector_type(4)));
typedef float f32x16 __attribute__((ext_vector_type(16)));

// ws layout:
//   ajs half8[N] 128KB ; ajb half8[N] 128KB
//   pf0/pf1 f16[N/16][16][16] : probs, J-TILED
//   scrap (>=2MB)             : probe sinks (pf clone @2MB, out clone @3MB)
#define WS_AJS 0
#define WS_AJB (N * 16)
#define WS_PF0 (N * 32)
#define WS_PF1 (N * 64)
#define WS_SCRAP (2 * 1024 * 1024)
#define PFIDX(n, c) ((((n) >> 4) * 16 + (c)) * 16 + ((n) & 15))

static __device__ __forceinline__ unsigned int pkexp(float a, float b) {
    float ea = __builtin_amdgcn_exp2f(a);
    float eb = __builtin_amdgcn_exp2f(b);
    return __builtin_bit_cast(unsigned int, __builtin_amdgcn_cvt_pkrtz(ea, eb));
}

static __device__ __forceinline__ half8 rdfrag(const unsigned int* R, int q) {
    uint2 lo = *(const uint2*)&R[2 * q];
    uint2 hi = *(const uint2*)&R[8 + 2 * q];
    half2 a = __builtin_bit_cast(half2, lo.x);
    half2 b = __builtin_bit_cast(half2, lo.y);
    half2 c = __builtin_bit_cast(half2, hi.x);
    half2 d = __builtin_bit_cast(half2, hi.y);
    half8 r = {a[0], a[1], b[0], b[1], c[0], c[1], d[0], d[1]};
    return r;
}

// once per launch: aug features + softmax(unaries) -> pf0 (tiled); zero rows 10..15 both
__global__ __launch_bounds__(256) void init_kernel(
    const float* __restrict__ unaries, const float* __restrict__ feat,
    half8* __restrict__ ajs8, half8* __restrict__ ajb8,
    _Float16* __restrict__ pf0, _Float16* __restrict__ pf1) {
    int n = blockIdx.x * 256 + threadIdx.x;
    float f6[6];
#pragma unroll
    for (int d = 0; d < 6; ++d) f6[d] = feat[d * N + n];
    float h3 = 0.5f * (f6[0] * f6[0] + f6[1] * f6[1] + f6[2] * f6[2]);
    float h6v = h3 + 0.5f * (f6[3] * f6[3] + f6[4] * f6[4] + f6[5] * f6[5]);
    half8 a = {};
    a[0] = (_Float16)(f6[0] * C3);
    a[1] = (_Float16)(f6[1] * C3);
    a[2] = (_Float16)(f6[2] * C3);
    a[6] = (_Float16)(-h3 * C3);
    a[7] = (_Float16)1.0f;
    ajs8[n] = a;
    half8 b;
#pragma unroll
    for (int d = 0; d < 6; ++d) b[d] = (_Float16)(f6[d] * LOG2E);
    b[6] = (_Float16)(-h6v * LOG2E);
    b[7] = (_Float16)1.0f;
    ajb8[n] = b;

    float q[C];
#pragma unroll
    for (int c = 0; c < C; ++c) q[c] = unaries[c * N + n];
    float m = q[0];
#pragma unroll
    for (int c = 1; c < C; ++c) m = fmaxf(m, q[c]);
    float e[C], s = 0.0f;
#pragma unroll
    for (int c = 0; c < C; ++c) {
        e[c] = __builtin_amdgcn_exp2f((q[c] - m) * LOG2E);
        s += e[c];
    }
    float inv = 1.0f / s;
#pragma unroll
    for (int c = 0; c < C; ++c) pf0[PFIDX(n, c)] = (_Float16)(e[c] * inv);
#pragma unroll
    for (int c = C; c < 16; ++c) {
        pf0[PFIDX(n, c)] = (_Float16)0.0f;
        pf1[PFIDX(n, c)] = (_Float16)0.0f;
    }
}

// Shared body: one full CRF iteration (B1 assumed in regs; main loop + epilogue).
// Used by the champion (1 call/dispatch) and probe_fused5 (5 calls/dispatch).
union FusedLds {
    unsigned int wt[16][2][32][18];
    float rbuf[16 * 1024];
};

static __device__ __forceinline__ void fused_body(
    FusedLds* sm, int t, int i0,
    const float* __restrict__ unaries, const float* __restrict__ SW,
    const float* __restrict__ BW, const float* __restrict__ CM,
    const char* __restrict__ ajs_c, const char* __restrict__ ajb_c,
    const _Float16* __restrict__ pf_in, _Float16* __restrict__ pf_out,
    float* __restrict__ out, int is_last, half8 b1s, half8 b1b) {
    int lane = t & 63;
    int w = t >> 6;
    int il = lane & 15;
    int quad = lane >> 4;
    int li = lane & 31;
    int hs = lane >> 5;
    const f32x4 zero4 = {0.f, 0.f, 0.f, 0.f};
    const f32x16 zero16 = {};

    f32x4 as0 = zero4, as1 = zero4, ab0 = zero4, ab1 = zero4;
    int jw = w * JW;
    const half4* pfv = (const half4*)pf_in;
    unsigned int* Ws = &sm->wt[w][0][li][0];
    unsigned int* Wb = &sm->wt[w][1][li][0];
    const unsigned int* R0s = &sm->wt[w][0][il][0];
    const unsigned int* R1s = &sm->wt[w][0][16 + il][0];
    const unsigned int* R0b = &sm->wt[w][1][il][0];
    const unsigned int* R1b = &sm->wt[w][1][16 + il][0];

    {
        int ph = w & 3;
        if (ph == 1) __builtin_amdgcn_s_sleep(2);
        else if (ph == 2) __builtin_amdgcn_s_sleep(4);
        else if (ph == 3) __builtin_amdgcn_s_sleep(6);
    }

    for (int k = 0; k < NS; ++k) {
        int j0 = jw + k * 32;
        half4 av_s = *(const half4*)(ajs_c + (size_t)(j0 + li) * 16 + hs * 8);
        half4 av_b = *(const half4*)(ajb_c + (size_t)(j0 + li) * 16 + hs * 8);
        half4 cp0 = pfv[((j0 >> 4) * 16 + il) * 4 + quad];
        half4 cp1 = pfv[(((j0 >> 4) + 1) * 16 + il) * 4 + quad];
        half8 A_s = {av_s[0], av_s[1], av_s[2], av_s[3], (_Float16)0.0f,
                     (_Float16)0.0f, (_Float16)0.0f, (_Float16)0.0f};
        half8 A_b = {av_b[0], av_b[1], av_b[2], av_b[3], (_Float16)0.0f,
                     (_Float16)0.0f, (_Float16)0.0f, (_Float16)0.0f};
        half8 Bp = {cp0[0], cp0[1], cp0[2], cp0[3], cp1[0], cp1[1], cp1[2], cp1[3]};

        __builtin_amdgcn_s_setprio(1);
        f32x16 d1s = __builtin_amdgcn_mfma_f32_32x32x16_f16(A_s, b1s, zero16, 0, 0, 0);
        f32x16 d1b = __builtin_amdgcn_mfma_f32_32x32x16_f16(A_b, b1b, zero16, 0, 0, 0);
        __builtin_amdgcn_s_setprio(0);

        {
            uint2 v;
            v.x = pkexp(d1s[0], d1s[1]);  v.y = pkexp(d1s[2], d1s[3]);
            *(uint2*)&Ws[0 + 2 * hs] = v;
            v.x = pkexp(d1s[4], d1s[5]);  v.y = pkexp(d1s[6], d1s[7]);
            *(uint2*)&Ws[4 + 2 * hs] = v;
            v.x = pkexp(d1s[8], d1s[9]);  v.y = pkexp(d1s[10], d1s[11]);
            *(uint2*)&Ws[8 + 2 * hs] = v;
            v.x = pkexp(d1s[12], d1s[13]); v.y = pkexp(d1s[14], d1s[15]);
            *(uint2*)&Ws[12 + 2 * hs] = v;
            v.x = pkexp(d1b[0], d1b[1]);  v.y = pkexp(d1b[2], d1b[3]);
            *(uint2*)&Wb[0 + 2 * hs] = v;
            v.x = pkexp(d1b[4], d1b[5]);  v.y = pkexp(d1b[6], d1b[7]);
            *(uint2*)&Wb[4 + 2 * hs] = v;
            v.x = pkexp(d1b[8], d1b[9]);  v.y = pkexp(d1b[10], d1b[11]);
            *(uint2*)&Wb[8 + 2 * hs] = v;
            v.x = pkexp(d1b[12], d1b[13]); v.y = pkexp(d1b[14], d1b[15]);
            *(uint2*)&Wb[12 + 2 * hs] = v;
        }
        half8 A00 = rdfrag(R0s, quad);
        half8 A01 = rdfrag(R1s, quad);
        half8 A10 = rdfrag(R0b, quad);
        half8 A11 = rdfrag(R1b, quad);
        __builtin_amdgcn_s_setprio(1);
        as0 = __builtin_amdgcn_mfma_f32_16x16x32_f16(A00, Bp, as0, 0, 0, 0);
        as1 = __builtin_amdgcn_mfma_f32_16x16x32_f16(A01, Bp, as1, 0, 0, 0);
        ab0 = __builtin_amdgcn_mfma_f32_16x16x32_f16(A10, Bp, ab0, 0, 0, 0);
        ab1 = __builtin_amdgcn_mfma_f32_16x16x32_f16(A11, Bp, ab1, 0, 0, 0);
        __builtin_amdgcn_s_setprio(0);
    }

    __syncthreads();
    {
        float* rb = sm->rbuf + w * 1024;
#pragma unroll
        for (int r = 0; r < 4; ++r) {
            rb[r * 64 + lane]       = as0[r];
            rb[256 + r * 64 + lane] = as1[r];
            rb[512 + r * 64 + lane] = ab0[r];
            rb[768 + r * 64 + lane] = ab1[r];
        }
    }
    __syncthreads();
    {
        float tot = 0.f;
#pragma unroll
        for (int w2 = 0; w2 < 16; ++w2) tot += sm->rbuf[w2 * 1024 + t];
        sm->rbuf[t] = tot;
    }
    __syncthreads();

    if (t < IBLK) {
        int i = i0 + t;
        int sub = t >> 4, ql = (t & 15) >> 2, rr = t & 3;
        float sp[C], bl[C];
#pragma unroll
        for (int c = 0; c < C; ++c) {
            int base = sub * 256 + rr * 64 + ql * 16 + c;
            sp[c] = sm->rbuf[base];
            bl[c] = sm->rbuf[base + 512];
        }
        float msg[C];
#pragma unroll
        for (int c = 0; c < C; ++c) {
            float m = 0.f;
#pragma unroll
            for (int kk = 0; kk < C; ++kk)
                m += SW[c * C + kk] * sp[kk] + BW[c * C + kk] * bl[kk];
            msg[c] = m;
        }
        float qq[C];
#pragma unroll
        for (int c = 0; c < C; ++c) {
            float pw = 0.f;
#pragma unroll
            for (int kk = 0; kk < C; ++kk) pw += CM[c * C + kk] * msg[kk];
            qq[c] = unaries[c * N + i] - pw;
        }
        if (is_last) {
#pragma unroll
            for (int c = 0; c < C; ++c) out[c * N + i] = qq[c];
        } else {
            float m = qq[0];
#pragma unroll
            for (int c = 1; c < C; ++c) m = fmaxf(m, qq[c]);
            float e[C], s = 0.0f;
#pragma unroll
            for (int c = 0; c < C; ++c) {
                e[c] = __builtin_amdgcn_exp2f((qq[c] - m) * LOG2E);
                s += e[c];
            }
            float inv = 1.0f / s;
#pragma unroll
            for (int c = 0; c < C; ++c) pf_out[PFIDX(i, c)] = (_Float16)(e[c] * inv);
        }
    }
}

static __device__ __forceinline__ void make_b1(
    const float* __restrict__ feat, int i0, int li, int hs,
    half8& b1s, half8& b1b) {
    int i = i0 + li;
    float g0 = feat[0 * N + i], g1 = feat[1 * N + i], g2 = feat[2 * N + i];
    float g3 = feat[3 * N + i], g4 = feat[4 * N + i], g5 = feat[5 * N + i];
    float h3 = 0.5f * (g0 * g0 + g1 * g1 + g2 * g2);
    float h6v = h3 + 0.5f * (g3 * g3 + g4 * g4 + g5 * g5);
    half4 slo = {(_Float16)g0, (_Float16)g1, (_Float16)g2, (_Float16)0.0f};
    half4 shi = {(_Float16)0.0f, (_Float16)0.0f, (_Float16)1.0f, (_Float16)(-h3 * C3)};
    half4 blo = {(_Float16)g0, (_Float16)g1, (_Float16)g2, (_Float16)g3};
    half4 bhi = {(_Float16)g4, (_Float16)g5, (_Float16)1.0f, (_Float16)(-h6v * LOG2E)};
    half4 sv = hs ? shi : slo;
    half4 bv = hs ? bhi : blo;
    half8 t1 = {sv[0], sv[1], sv[2], sv[3], (_Float16)0.0f, (_Float16)0.0f,
                (_Float16)0.0f, (_Float16)0.0f};
    half8 t2 = {bv[0], bv[1], bv[2], bv[3], (_Float16)0.0f, (_Float16)0.0f,
                (_Float16)0.0f, (_Float16)0.0f};
    b1s = t1;
    b1b = t2;
}

// ============================ champion (R13, 162us) ============================
__global__ __launch_bounds__(FBLOCK, 4) void fused_kernel(
    const float* __restrict__ unaries, const float* __restrict__ feat,
    const float* __restrict__ SW, const float* __restrict__ BW,
    const float* __restrict__ CM,
    const char* __restrict__ ajs_c, const char* __restrict__ ajb_c,
    const _Float16* __restrict__ pf_in, _Float16* __restrict__ pf_out,
    float* __restrict__ out, int is_last) {
    __shared__ FusedLds sm;
    int t = threadIdx.x;
    int i0 = blockIdx.x * IBLK;
    half8 b1s, b1b;
    make_b1(feat, i0, t & 31 /*li of lane*/, (t & 63) >> 5, b1s, b1b);
    fused_body(&sm, t, i0, unaries, SW, BW, CM, ajs_c, ajb_c, pf_in, pf_out, out,
               is_last, b1s, b1b);
}

// ============ probe: 5 full fused bodies in ONE kernel (no boundaries) ============
// Reads real inputs; pf/out writes go to scrap clones; always reads pf0
// (stale data across internal iterations is fine for timing).
__global__ __launch_bounds__(FBLOCK, 4) void probe_fused5(
    const float* __restrict__ unaries, const float* __restrict__ feat,
    const float* __restrict__ SW, const float* __restrict__ BW,
    const float* __restrict__ CM,
    const char* __restrict__ ajs_c, const char* __restrict__ ajb_c,
    const _Float16* __restrict__ pf_in, _Float16* __restrict__ pf_scrap,
    float* __restrict__ out_scrap) {
    __shared__ FusedLds sm;
    int t = threadIdx.x;
    int i0 = blockIdx.x * IBLK;
    half8 b1s, b1b;
    make_b1(feat, i0, t & 31, (t & 63) >> 5, b1s, b1b);
    for (int itr = 0; itr < NUM_ITERS; ++itr) {
        fused_body(&sm, t, i0, unaries, SW, BW, CM, ajs_c, ajb_c, pf_in, pf_scrap,
                   out_scrap, itr == NUM_ITERS - 1 ? 1 : 0, b1s, b1b);
        __syncthreads();   // wt/rbuf reuse across internal iterations
    }
}

extern "C" void kernel_launch(void* const* d_in, const int* in_sizes, int n_in,
                              void* d_out, int out_size, void* d_ws, size_t ws_size,
                              hipStream_t stream) {
    const float* unaries = (const float*)d_in[0];   // [10, 8192]
    const float* feat    = (const float*)d_in[1];   // [6, 8192]
    const float* SW      = (const float*)d_in[2];   // [10,10]
    const float* BW      = (const float*)d_in[3];   // [10,10]
    const float* CM      = (const float*)d_in[4];   // [10,10]
    float* out = (float*)d_out;

    char* ws = (char*)d_ws;
    half8* ajs    = (half8*)(ws + WS_AJS);
    half8* ajb    = (half8*)(ws + WS_AJB);
    _Float16* pf0 = (_Float16*)(ws + WS_PF0);
    _Float16* pf1 = (_Float16*)(ws + WS_PF1);
    _Float16* pf_scrap = (_Float16*)(ws + WS_SCRAP);
    float* out_scrap   = (float*)(ws + WS_SCRAP + 1024 * 1024);

    init_kernel<<<N / 256, 256, 0, stream>>>(unaries, feat, ajs, ajb, pf0, pf1);
    const _Float16* pin = pf0;
    _Float16* pout = pf1;
    for (int it = 1; it <= NUM_ITERS; ++it) {
        fused_kernel<<<NBLK, FBLOCK, 0, stream>>>(
            unaries, feat, SW, BW, CM, (const char*)ajs, (const char*)ajb,
            pin, pout, out, it == NUM_ITERS ? 1 : 0);
        const _Float16* tmp = pout;
        pout = (_Float16*)pin;
        pin = tmp;
    }
    // -------- diagnostic (scrap-only; removed next round) --------
    probe_fused5<<<NBLK, FBLOCK, 0, stream>>>(
        unaries, feat, SW, BW, CM, (const char*)ajs, (const char*)ajb,
        pf0, pf_scrap, out_scrap);
}